// Round 9
// baseline (226.807 us; speedup 1.0000x reference)
//
#include <hip/hip_runtime.h>
#include <hip/hip_fp16.h>
#include <cstdint>
#include <cstddef>

#define NNODES 8192
#define NEDGES 262144
#define MAXDEG 96          // mean degree 32, sigma 5.7 -> +11 sigma headroom
#define SMEM_BYTES 10496   // max over phases: gemm As(5120)+Bs(5120)+cs(256)

typedef _Float16 f16x8 __attribute__((ext_vector_type(8)));
typedef _Float16 h2v   __attribute__((ext_vector_type(2)));
typedef float    f32x4 __attribute__((ext_vector_type(4)));

__device__ __forceinline__ float leaky(float v){ return v > 0.f ? v : 0.01f*v; }

__device__ __forceinline__ unsigned fmap(float f){
  unsigned u = __float_as_uint(f);
  return (u & 0x80000000u) ? ~u : (u | 0x80000000u);
}
__device__ __forceinline__ float funmap(unsigned u){
  return (u & 0x80000000u) ? __uint_as_float(u & 0x7FFFFFFFu) : __uint_as_float(~u);
}
__device__ __forceinline__ h2v as_h2(unsigned u){
  union{ unsigned x; h2v h; } c; c.x = u; return c.h;
}

// ---------------- all device pointers in one struct (single kernel arg) ----------
struct GP {
  const float *x; const int *ei;
  const float *W1,*b1,*W2,*b2,*W3,*b3,*Wk,*bk,*Wq,*bq,*Wr,*br,*lng,*lnb,*Wf,*bfv;
  float* out;
  __half *xw1h,*h1h,*h2h,*qth,*gh,*hw3h;
  float *resid,*sw3;
  __half *Wqkt,*W2t,*W3t;
  float *bqk,*wb,*s0p;
  int *degc,*degr,*csrc,*csrd;
  unsigned* poolpart;
};

// ---------------- MFMA GEMM tile, f16 inputs: C64x64 = A[.,K] @ Bt[.,K]^T -----------
__device__ __forceinline__ void gemm_tile(const __half* __restrict__ A,
    const __half* __restrict__ Bt, const float* __restrict__ bias,
    float* __restrict__ Cf, __half* __restrict__ Ch, float* __restrict__ csum,
    int K, int N, int act, int bx, int by,
    _Float16 (*As)[40], _Float16 (*Bs)[40], float* cs){
  int t = threadIdx.x, w = t>>6, lane = t&63;
  int m0 = bx*64, n0 = by*64;
  int quad = lane>>4, l15 = lane&15;
  int srow = t>>2, soff = (t&3)*8;
  f32x4 acc0 = {0.f,0.f,0.f,0.f}, acc1 = acc0, acc2 = acc0, acc3 = acc0;
  for (int k0 = 0; k0 < K; k0 += 32){
    *(uint4*)&As[srow][soff] = *(const uint4*)(A  + (size_t)(m0+srow)*K + k0 + soff);
    *(uint4*)&Bs[srow][soff] = *(const uint4*)(Bt + (size_t)(n0+srow)*K + k0 + soff);
    __syncthreads();
    f16x8 af = *(const f16x8*)&As[w*16 + l15][quad*8];
    f16x8 b0 = *(const f16x8*)&Bs[ 0 + l15][quad*8];
    f16x8 b1 = *(const f16x8*)&Bs[16 + l15][quad*8];
    f16x8 b2 = *(const f16x8*)&Bs[32 + l15][quad*8];
    f16x8 b3 = *(const f16x8*)&Bs[48 + l15][quad*8];
    acc0 = __builtin_amdgcn_mfma_f32_16x16x32_f16(af, b0, acc0, 0,0,0);
    acc1 = __builtin_amdgcn_mfma_f32_16x16x32_f16(af, b1, acc1, 0,0,0);
    acc2 = __builtin_amdgcn_mfma_f32_16x16x32_f16(af, b2, acc2, 0,0,0);
    acc3 = __builtin_amdgcn_mfma_f32_16x16x32_f16(af, b3, acc3, 0,0,0);
    __syncthreads();
  }
  f32x4 accs[4] = {acc0, acc1, acc2, acc3};
  if (csum){
    if (t < 64) cs[t] = 0.f;
    __syncthreads();
    #pragma unroll
    for (int nt=0; nt<4; ++nt){
      float pp = accs[nt][0]+accs[nt][1]+accs[nt][2]+accs[nt][3];
      atomicAdd(&cs[nt*16 + l15], pp);
    }
    __syncthreads();
    if (t < 64) atomicAdd(&csum[n0 + t], cs[t]);
  }
  #pragma unroll
  for (int nt=0; nt<4; ++nt){
    int col = n0 + nt*16 + l15;
    float bv = bias ? bias[col] : 0.f;
    #pragma unroll
    for (int r=0;r<4;r++){
      int row = m0 + w*16 + quad*4 + r;
      float v = accs[nt][r] + bv;
      if (act) v = leaky(v);
      if (Cf) Cf[(size_t)row*N + col] = v;
      if (Ch) Ch[(size_t)row*N + col] = __float2half(v);
    }
  }
}

// -------- MFMA GEMM tile, f32 inputs converted during LDS staging ------------------
template<int TRANSB>
__device__ __forceinline__ void gemm_f32(const float* __restrict__ A,
    const float* __restrict__ B, const float* __restrict__ bias,
    float* __restrict__ Cf, __half* __restrict__ Ch,
    int K, int N, int bx, int by,
    _Float16 (*As)[40], _Float16 (*Bs)[40]){
  int t = threadIdx.x, w = t>>6, lane = t&63;
  int m0 = bx*64, n0 = by*64;
  int quad = lane>>4, l15 = lane&15;
  int srow = t>>2, soff = (t&3)*8;
  f32x4 acc0 = {0.f,0.f,0.f,0.f}, acc1 = acc0, acc2 = acc0, acc3 = acc0;
  for (int k0 = 0; k0 < K; k0 += 32){
    float4 a0 = *(const float4*)(A + (size_t)(m0+srow)*K + k0 + soff);
    float4 a1 = *(const float4*)(A + (size_t)(m0+srow)*K + k0 + soff + 4);
    _Float16* ad = &As[srow][soff];
    ad[0]=(_Float16)a0.x; ad[1]=(_Float16)a0.y; ad[2]=(_Float16)a0.z; ad[3]=(_Float16)a0.w;
    ad[4]=(_Float16)a1.x; ad[5]=(_Float16)a1.y; ad[6]=(_Float16)a1.z; ad[7]=(_Float16)a1.w;
    _Float16* bd = &Bs[srow][soff];
    if (TRANSB){
      #pragma unroll
      for (int u=0;u<8;u++)
        bd[u] = (_Float16)B[(size_t)(k0+soff+u)*N + n0+srow];
    } else {
      float4 b0 = *(const float4*)(B + (size_t)(n0+srow)*K + k0 + soff);
      float4 b1 = *(const float4*)(B + (size_t)(n0+srow)*K + k0 + soff + 4);
      bd[0]=(_Float16)b0.x; bd[1]=(_Float16)b0.y; bd[2]=(_Float16)b0.z; bd[3]=(_Float16)b0.w;
      bd[4]=(_Float16)b1.x; bd[5]=(_Float16)b1.y; bd[6]=(_Float16)b1.z; bd[7]=(_Float16)b1.w;
    }
    __syncthreads();
    f16x8 af = *(const f16x8*)&As[w*16 + l15][quad*8];
    f16x8 b0 = *(const f16x8*)&Bs[ 0 + l15][quad*8];
    f16x8 b1 = *(const f16x8*)&Bs[16 + l15][quad*8];
    f16x8 b2 = *(const f16x8*)&Bs[32 + l15][quad*8];
    f16x8 b3 = *(const f16x8*)&Bs[48 + l15][quad*8];
    acc0 = __builtin_amdgcn_mfma_f32_16x16x32_f16(af, b0, acc0, 0,0,0);
    acc1 = __builtin_amdgcn_mfma_f32_16x16x32_f16(af, b1, acc1, 0,0,0);
    acc2 = __builtin_amdgcn_mfma_f32_16x16x32_f16(af, b2, acc2, 0,0,0);
    acc3 = __builtin_amdgcn_mfma_f32_16x16x32_f16(af, b3, acc3, 0,0,0);
    __syncthreads();
  }
  f32x4 accs[4] = {acc0, acc1, acc2, acc3};
  #pragma unroll
  for (int nt=0; nt<4; ++nt){
    int col = n0 + nt*16 + l15;
    float bv = bias ? bias[col] : 0.f;
    #pragma unroll
    for (int r=0;r<4;r++){
      int row = m0 + w*16 + quad*4 + r;
      float v = accs[nt][r] + bv;
      if (Cf) Cf[(size_t)row*N + col] = v;
      if (Ch) Ch[(size_t)row*N + col] = __float2half(v);
    }
  }
}

// -------- GCN aggregation F=128, WAVE-PER-NODE, ILP-8 over padded buckets ---------
template<int INS, int OUTS, int ACT>
__device__ __forceinline__ void agg128w(const __half* __restrict__ in,
    const int* __restrict__ deg, const int* __restrict__ src,
    __half* __restrict__ outp, const float* __restrict__ bias, int i){
  int lane = threadIdx.x & 63;
  int dcc = deg[i];
  float dc = rsqrtf((float)(dcc+1));
  int e0 = i*MAXDEG, e1 = e0 + dcc;
  float2 acc = make_float2(0.f, 0.f);
  for (int eb = e0; eb < e1; eb += 8){
    int m = e1 - eb; if (m > 8) m = 8;
    int r[8];
    #pragma unroll
    for (int u=0;u<8;u++) r[u] = src[(u<m) ? eb+u : eb];
    __half2 hv[8]; float sc[8];
    #pragma unroll
    for (int u=0;u<8;u++){
      hv[u] = *(const __half2*)(in + (size_t)r[u]*128 + lane*2);
      sc[u] = INS ? 1.f : rsqrtf((float)(deg[r[u]]+1));
    }
    #pragma unroll
    for (int u=0;u<8;u++){
      if (u < m){
        float2 h = __half22float2(hv[u]);
        if (INS){ acc.x += h.x; acc.y += h.y; }
        else { acc.x = fmaf(sc[u], h.x, acc.x); acc.y = fmaf(sc[u], h.y, acc.y); }
      }
    }
  }
  float2 self = __half22float2(*(const __half2*)(in + (size_t)i*128 + lane*2));
  float ss = INS ? 1.f : dc;
  float ox = dc*(ss*self.x + acc.x);
  float oy = dc*(ss*self.y + acc.y);
  if (ACT){
    ox = leaky(ox + bias[lane*2]);
    oy = leaky(oy + bias[lane*2+1]);
  }
  if (OUTS){ ox *= dc; oy *= dc; }
  *(__half2*)(outp + (size_t)i*128 + lane*2) = __floats2half2_rn(ox, oy);
}

// ------- fused attention, wave-per-node, 8-edge ILP, fold-packed wave reduction ------
__device__ __forceinline__ void attn_unit(const GP& p, int u){
  const int n = NNODES;
  int w = threadIdx.x>>6, lane = threadIdx.x&63;
  int i = u*4 + w;
  int fo = lane*4;
  uint2 qtu = *(const uint2*)(p.qth + (size_t)i*256 + fo);
  h2v q0 = as_h2(qtu.x), q1 = as_h2(qtu.y);
  float4 wbv = *(const float4*)(p.wb + fo);
  uint2 hiu  = *(const uint2*)(p.h2h + (size_t)i*256 + fo);
  float2 hia = __half22float2(*(__half2*)&hiu.x);
  float2 hib = __half22float2(*(__half2*)&hiu.y);
  float pv = hia.x*wbv.x + hia.y*wbv.y + hib.x*wbv.z + hib.y*wbv.w;
  #pragma unroll
  for (int mm=32; mm; mm>>=1) pv += __shfl_xor(pv, mm, 64);
  float base = pv + p.s0p[0];          // we = exp(d + pv + s0) == Ei*exp(d)
  int dri = p.degr[i];
  int e0 = i*MAXDEG, e1 = e0 + dri;
  float acc = 0.f, dsum = 0.f;
  int slot = lane & 7;
  for (int eb = e0; eb < e1; eb += 8){
    int m = e1 - eb; if (m > 8) m = 8;
    int j[8];
    #pragma unroll
    for (int u8=0;u8<8;u8++) j[u8] = p.csrd[(u8<m) ? eb+u8 : eb];
    uint2 hv[8]; float gv[8];
    #pragma unroll
    for (int u8=0;u8<8;u8++){
      hv[u8] = *(const uint2*)(p.h2h + (size_t)j[u8]*256 + fo);
      gv[u8] = __half2float(p.gh[(size_t)j[u8]*64 + lane]);
    }
    float d[8];
    #pragma unroll
    for (int u8=0;u8<8;u8++)
      d[u8] = __builtin_amdgcn_fdot2(q1, as_h2(hv[u8].y),
              __builtin_amdgcn_fdot2(q0, as_h2(hv[u8].x), 0.f, false), false);
    // ---- fold-packed 8-value reduction ----
    #pragma unroll
    for (int v=0;v<8;v++) d[v] += __shfl_xor(d[v], 1, 64);     // dup across bit0
    float e0_ = (lane&1) ? d[1] : d[0];
    float e1_ = (lane&1) ? d[3] : d[2];
    float e2_ = (lane&1) ? d[5] : d[4];
    float e3_ = (lane&1) ? d[7] : d[6];
    e0_ += __shfl_xor(e0_, 2, 64);  e1_ += __shfl_xor(e1_, 2, 64);  // dup bit1
    e2_ += __shfl_xor(e2_, 2, 64);  e3_ += __shfl_xor(e3_, 2, 64);
    float f0_ = (lane&2) ? e1_ : e0_;
    float f1_ = (lane&2) ? e3_ : e2_;
    f0_ += __shfl_xor(f0_, 4, 64);  f1_ += __shfl_xor(f1_, 4, 64);  // dup bit2
    float g_ = (lane&4) ? f1_ : f0_;          // lane l carries neighbor l&7
    g_ += __shfl_xor(g_,  8, 64);
    g_ += __shfl_xor(g_, 16, 64);
    g_ += __shfl_xor(g_, 32, 64);             // full 64-lane dot, dup across bits 3..5
    float wep = __expf(g_ + base);            // one exp covers 8 neighbors
    float wm = (slot < m) ? wep : 0.f;
    wm += __shfl_xor(wm, 1, 64);
    wm += __shfl_xor(wm, 2, 64);
    wm += __shfl_xor(wm, 4, 64);              // uniform across wave
    dsum += wm;
    #pragma unroll
    for (int u8=0;u8<8;u8++){
      if (u8 < m){
        float wu = __shfl(wep, u8, 64);
        acc = fmaf(wu - 1.f, gv[u8], acc);
      }
    }
  }
  float inv = 1.0f / ((float)(n - dri) + dsum);
  float di = rsqrtf((float)(p.degc[i]+1));
  p.hw3h[(size_t)i*64 + lane] = __float2half(di * (p.sw3[lane] + acc) * inv);
}

// ------- conv3 agg (pre-scaled input) + bias + leaky + residual + LN + pool ---------
__device__ __forceinline__ void zp_wave(const GP& p, int c){
  int lane = threadIdx.x & 63;
  int dcc = p.degc[c];
  float dc = rsqrtf((float)(dcc+1));
  float acc = 0.f;
  int e0 = c*MAXDEG, e1 = e0 + dcc;
  for (int eb = e0; eb < e1; eb += 8){
    int m = e1 - eb; if (m > 8) m = 8;
    int r[8];
    #pragma unroll
    for (int u=0;u<8;u++) r[u] = p.csrc[(u<m) ? eb+u : eb];
    __half hval[8];
    #pragma unroll
    for (int u=0;u<8;u++) hval[u] = p.hw3h[(size_t)r[u]*64 + lane];
    #pragma unroll
    for (int u=0;u<8;u++)
      if (u < m) acc += __half2float(hval[u]);
  }
  float self = __half2float(p.hw3h[(size_t)c*64 + lane]);   // pre-scaled by d_c
  float v = leaky(dc*(self + acc) + p.b3[lane]) + p.resid[(size_t)c*64 + lane];
  float s = v;
  #pragma unroll
  for (int mm=32; mm; mm>>=1) s += __shfl_xor(s, mm, 64);
  float mu = s * (1.0f/64.0f);
  float d = v - mu;
  float s2 = d*d;
  #pragma unroll
  for (int mm=32; mm; mm>>=1) s2 += __shfl_xor(s2, mm, 64);
  float zv = d * rsqrtf(s2*(1.0f/64.0f) + 1e-5f) * p.lng[lane] + p.lnb[lane];
  atomicMax(&p.poolpart[(c & 63)*64 + lane], fmap(zv));
}

// ---------------- final: reduce poolpart buckets + 64x16 matvec ----------------
__device__ __forceinline__ void final_unit(const GP& p, char* smem){
  int t = threadIdx.x, f = t & 63, g = t >> 6;
  unsigned (*sm)[64] = (unsigned(*)[64])smem;
  float* pool = (float*)(smem + 1024);
  unsigned mu = 0u;
  for (int b = g; b < 64; b += 4) mu = max(mu, p.poolpart[b*64 + f]);
  sm[g][f] = mu;
  __syncthreads();
  if (g == 0)
    pool[f] = funmap(max(max(sm[0][f],sm[1][f]), max(sm[2][f],sm[3][f])));
  __syncthreads();
  if (t < 16){
    float a = p.bfv[t];
    #pragma unroll
    for (int ff=0; ff<64; ++ff) a = fmaf(pool[ff], p.Wf[ff*16 + t], a);
    p.out[t] = a;
  }
}

// ======================= kernels =====================
// k_z: zero deg arrays + ALL input-only prep (fills the former 16-block idle ramp)
// [0,16): zero degc/degr int4 | [16,144): W2t | [144,208): W3t
// [208,224): zero poolpart | 224: zero sw3 | [225,481): smallvec
__global__ __launch_bounds__(256) void k_z(GP p){
  __shared__ float smv[768];
  int b = blockIdx.x, t = threadIdx.x;
  if (b < 16){
    int idx = b*256 + t;
    int4 z = {0,0,0,0};
    ((int4*)p.degc)[idx] = z;
  } else if (b < 144){             // W2[128][256] -> W2t[256][128]
    int idx = (b-16)*256 + t;
    int nn = idx >> 7, k = idx & 127;
    p.W2t[idx] = __float2half(p.W2[k*256 + nn]);
  } else if (b < 208){             // W3[256][64] -> W3t[64][256]
    int idx = (b-144)*256 + t;
    int nn = idx >> 8, k = idx & 255;
    p.W3t[idx] = __float2half(p.W3[k*64 + nn]);
  } else if (b < 224){
    p.poolpart[(b-208)*256 + t] = 0u;
  } else if (b == 224){
    if (t < 64) p.sw3[t] = 0.f;
  } else {                         // smallvec: coalesced row read + block reduce
    int c = b - 225;
    float* ra = smv; float* rb = smv + 256; float* rc = smv + 512;
    ra[t] = p.Wk[c*256 + t] * p.bq[t];
    rb[t] = p.Wq[c*256 + t] * p.bk[t];
    if (c == 0) rc[t] = p.bq[t]*p.bk[t];
    __syncthreads();
    for (int off=128; off; off>>=1){
      if (t < off){
        ra[t] += ra[t+off];
        rb[t] += rb[t+off];
        if (c == 0) rc[t] += rc[t+off];
      }
      __syncthreads();
    }
    if (t == 0){
      p.bqk[c] = ra[0];
      p.wb[c]  = rb[0];
      if (c == 0) p.s0p[0] = rc[0];
    }
  }
}

// k_pre: CSR scatter + xw1/Wqkt/resid GEMMs (f32-staged)
// [0,1024): scatter | [1024,1280): xw1 | [1280,1296): Wqkt | [1296,1424): resid
__global__ __launch_bounds__(256) void k_pre(GP p){
  __shared__ __align__(16) char smem[SMEM_BYTES];
  _Float16 (*As)[40] = (_Float16(*)[40])smem;
  _Float16 (*Bs)[40] = (_Float16(*)[40])(smem + 5120);
  int b = blockIdx.x, t = threadIdx.x;
  if (b < 1024){
    int e = b*256 + t;
    int r = p.ei[e], c = p.ei[NEDGES+e];
    int p1 = atomicAdd(&p.degc[c],1); p.csrc[c*MAXDEG + p1] = r;
    int p2 = atomicAdd(&p.degr[r],1); p.csrd[r*MAXDEG + p2] = c;
  } else if (b < 1280){            // xw1 = x@W1 (B transposed-staged from f32)
    int bb = b - 1024;
    gemm_f32<1>(p.x, p.W1, nullptr, nullptr, p.xw1h, 128, 128, bb>>1, bb&1, As, Bs);
  } else if (b < 1296){            // Wqkt = Wk@Wq^T (both f32 direct)
    int bb = b - 1280;
    gemm_f32<0>(p.Wk, p.Wq, nullptr, nullptr, p.Wqkt, 256, 256, bb&3, bb>>2, As, Bs);
  } else {                         // resid = x@Wr + br
    gemm_f32<1>(p.x, p.Wr, p.br, p.resid, nullptr, 128, 64, b-1296, 0, As, Bs);
  }
}

// conv1 aggregate (+bias+leaky), output pre-scaled by d_c -> h1'
__global__ __launch_bounds__(256) void k_agg0(GP p){
  int i = blockIdx.x*4 + (threadIdx.x>>6);
  agg128w<0,1,1>(p.xw1h, p.degc, p.csrc, p.h1h, p.b1, i);
}

// FUSED conv2 aggregate + transform: block owns 32 rows.
// Phase A: each wave aggregates 8 nodes from h1h (pre-scaled) into LDS tile.
// Phase B: h2 = leaky(h1a_LDS @ W2t + b2); wave = (row-group rg, col-half ch).
// Numerics bit-identical to the old agg1->h1ah->gemm2 path.
__global__ __launch_bounds__(256) void k_ag2(GP p){
  __shared__ _Float16 h1a[32][136];     // 8.7KB, +8 half pad (bank rotation)
  __shared__ _Float16 Bs2[256][40];     // 20KB: full W2t K-slice, padded
  int t = threadIdx.x, w = t>>6, lane = t&63;
  int base = blockIdx.x*32;
  // ---- phase A ----
  for (int q=0; q<8; ++q){
    int i = base + w*8 + q;
    int dcc = p.degc[i];
    float dc = rsqrtf((float)(dcc+1));
    int e0 = i*MAXDEG, e1 = e0 + dcc;
    float2 acc = make_float2(0.f, 0.f);
    for (int eb=e0; eb<e1; eb+=8){
      int m = e1-eb; if (m>8) m=8;
      int r[8];
      #pragma unroll
      for (int u=0;u<8;u++) r[u] = p.csrc[(u<m)?eb+u:eb];
      __half2 hv[8];
      #pragma unroll
      for (int u=0;u<8;u++) hv[u] = *(const __half2*)(p.h1h + (size_t)r[u]*128 + lane*2);
      #pragma unroll
      for (int u=0;u<8;u++){
        if (u<m){ float2 h=__half22float2(hv[u]); acc.x+=h.x; acc.y+=h.y; }
      }
    }
    float2 self = __half22float2(*(const __half2*)(p.h1h + (size_t)i*128 + lane*2));
    *(__half2*)&h1a[w*8+q][lane*2] = __floats2half2_rn(dc*(self.x+acc.x), dc*(self.y+acc.y));
  }
  __syncthreads();
  // ---- phase B ----
  int quad = lane>>4, l15 = lane&15;
  int rg = w&1, ch = w>>1;              // row-group (0,1), col-half (0,1)
  f32x4 acc[8];
  #pragma unroll
  for (int nt=0;nt<8;++nt) acc[nt] = (f32x4){0.f,0.f,0.f,0.f};
  for (int k0=0;k0<128;k0+=32){
    #pragma unroll
    for (int pp=0;pp<4;pp++){
      int row = pp*64 + (t>>2);
      *(uint4*)&Bs2[row][(t&3)*8] = *(const uint4*)(p.W2t + (size_t)row*128 + k0 + (t&3)*8);
    }
    __syncthreads();
    f16x8 af = *(const f16x8*)&h1a[rg*16 + l15][k0 + quad*8];
    #pragma unroll
    for (int nt=0; nt<8; ++nt){
      f16x8 bf = *(const f16x8*)&Bs2[ch*128 + nt*16 + l15][quad*8];
      acc[nt] = __builtin_amdgcn_mfma_f32_16x16x32_f16(af, bf, acc[nt], 0,0,0);
    }
    __syncthreads();
  }
  #pragma unroll
  for (int nt=0;nt<8;++nt){
    int col = ch*128 + nt*16 + l15;
    float bv = p.b2[col];
    #pragma unroll
    for (int r=0;r<4;r++){
      int row = base + rg*16 + quad*4 + r;
      float v = leaky(acc[nt][r] + bv);
      p.h2h[(size_t)row*256 + col] = __float2half(v);
    }
  }
}

// G = h2@W3 (+colsum) and qt = h2@Wqk + bqk
__global__ __launch_bounds__(256) void k_mix2(GP p){
  __shared__ __align__(16) char smem[SMEM_BYTES];
  _Float16 (*As)[40] = (_Float16(*)[40])smem;
  _Float16 (*Bs)[40] = (_Float16(*)[40])(smem + 5120);
  float* cs = (float*)(smem + 10240);
  int b = blockIdx.x;
  if (b < 128) gemm_tile(p.h2h, p.W3t, nullptr, nullptr, p.gh, p.sw3, 256, 64, 0, b, 0, As, Bs, cs);
  else {
    int bb = b - 128;
    gemm_tile(p.h2h, p.Wqkt, p.bqk, nullptr, p.qth, nullptr, 256, 256, 0, bb>>2, bb&3, As, Bs, cs);
  }
}

__global__ __launch_bounds__(256) void k_attn(GP p){ attn_unit(p, blockIdx.x); }

__global__ __launch_bounds__(256) void k_zp(GP p){
  int c = blockIdx.x*4 + (threadIdx.x>>6);
  zp_wave(p, c);
}

__global__ __launch_bounds__(256) void k_final(GP p){
  __shared__ __align__(16) char smem[SMEM_BYTES];
  final_unit(p, smem);
}

extern "C" void kernel_launch(void* const* d_in, const int* in_sizes, int n_in,
                              void* d_out, int out_size, void* d_ws, size_t ws_size,
                              hipStream_t stream){
  const int n = NNODES, E = NEDGES;
  char* ws = (char*)d_ws; size_t off = 0;
  auto alloc = [&](size_t bytes)->void*{
    void* pp = ws + off; off += (bytes + 255) & ~(size_t)255; return pp;
  };
  GP p;
  p.x   = (const float*)d_in[0];
  p.ei  = (const int*)d_in[1];
  p.W1  = (const float*)d_in[2];  p.b1 = (const float*)d_in[3];
  p.W2  = (const float*)d_in[4];  p.b2 = (const float*)d_in[5];
  p.W3  = (const float*)d_in[6];  p.b3 = (const float*)d_in[7];
  p.Wk  = (const float*)d_in[8];  p.bk = (const float*)d_in[9];
  p.Wq  = (const float*)d_in[10]; p.bq = (const float*)d_in[11];
  p.Wr  = (const float*)d_in[12]; p.br = (const float*)d_in[13];
  p.lng = (const float*)d_in[14]; p.lnb = (const float*)d_in[15];
  p.Wf  = (const float*)d_in[16]; p.bfv = (const float*)d_in[17];
  p.out = (float*)d_out;

  // degc+degr contiguous (zeroed together by k_z)
  p.degc = (int*)alloc((size_t)n*4);
  p.degr = (int*)alloc((size_t)n*4);
  p.xw1h = (__half*)alloc((size_t)n*128*2);
  p.h1h  = (__half*)alloc((size_t)n*128*2);
  p.h2h  = (__half*)alloc((size_t)n*256*2);
  p.qth  = (__half*)alloc((size_t)n*256*2);
  p.gh   = (__half*)alloc((size_t)n*64*2);
  p.hw3h = (__half*)alloc((size_t)n*64*2);
  p.resid= (float*)alloc((size_t)n*64*4);
  p.sw3  = (float*)alloc(64*4);
  p.Wqkt = (__half*)alloc(256*256*2);
  p.W2t  = (__half*)alloc(128*256*2);
  p.W3t  = (__half*)alloc(256*64*2);
  p.bqk  = (float*)alloc(256*4);
  p.wb   = (float*)alloc(256*4);
  p.s0p  = (float*)alloc(4);
  p.csrc = (int*)alloc((size_t)n*MAXDEG*4);
  p.csrd = (int*)alloc((size_t)n*MAXDEG*4);
  p.poolpart = (unsigned*)alloc(64*64*4);

  k_z    <<<dim3(481),  256, 0, stream>>>(p);   // zero deg + transposes + smallvec
  k_pre  <<<dim3(1424), 256, 0, stream>>>(p);   // scatter + xw1/Wqkt/resid gemms
  k_agg0 <<<dim3(n/4),  256, 0, stream>>>(p);   // conv1 agg + bias + leaky, pre-scaled out
  k_ag2  <<<dim3(n/32), 256, 0, stream>>>(p);   // FUSED conv2 agg + transform -> h2
  k_mix2 <<<dim3(640),  256, 0, stream>>>(p);   // G=h2@W3 (+colsum), qt=h2@Wqk+bqk
  k_attn <<<dim3(n/4),  256, 0, stream>>>(p);   // fused attention (packed reduce)
  k_zp   <<<dim3(n/4),  256, 0, stream>>>(p);   // conv3 agg+resid+LN+pool (wave/node)
  k_final<<<dim3(1),    256, 0, stream>>>(p);   // bucket reduce + matvec
}

// Round 10
// 203.315 us; speedup vs baseline: 1.1155x; 1.1155x over previous
//
#include <hip/hip_runtime.h>
#include <hip/hip_fp16.h>
#include <cstdint>
#include <cstddef>

#define NNODES 8192
#define NEDGES 262144
#define MAXDEG 96          // mean degree 32, sigma 5.7 -> +11 sigma headroom
#define SMEM_BYTES 10496   // max over phases: gemm As(5120)+Bs(5120)+cs(256)

typedef _Float16 f16x8 __attribute__((ext_vector_type(8)));
typedef _Float16 h2v   __attribute__((ext_vector_type(2)));
typedef float    f32x4 __attribute__((ext_vector_type(4)));

__device__ __forceinline__ float leaky(float v){ return v > 0.f ? v : 0.01f*v; }

__device__ __forceinline__ unsigned fmap(float f){
  unsigned u = __float_as_uint(f);
  return (u & 0x80000000u) ? ~u : (u | 0x80000000u);
}
__device__ __forceinline__ float funmap(unsigned u){
  return (u & 0x80000000u) ? __uint_as_float(u & 0x7FFFFFFFu) : __uint_as_float(~u);
}
__device__ __forceinline__ h2v as_h2(unsigned u){
  union{ unsigned x; h2v h; } c; c.x = u; return c.h;
}

// ---------------- all device pointers in one struct (single kernel arg) ----------
struct GP {
  const float *x; const int *ei;
  const float *W1,*b1,*W2,*b2,*W3,*b3,*Wk,*bk,*Wq,*bq,*Wr,*br,*lng,*lnb,*Wf,*bfv;
  float* out;
  __half *xw1h,*h1h,*h1ah,*h2h,*qth,*gh,*hw3h;
  float *resid,*sw3;
  __half *Wqkt,*W2t,*W3t;
  float *bqk,*wb,*s0p;
  int *degc,*degr,*csrc,*csrd;
  unsigned* poolpart;
};

// ---------------- MFMA GEMM tile, f16 inputs: C64x64 = A[.,K] @ Bt[.,K]^T -----------
__device__ __forceinline__ void gemm_tile(const __half* __restrict__ A,
    const __half* __restrict__ Bt, const float* __restrict__ bias,
    float* __restrict__ Cf, __half* __restrict__ Ch, float* __restrict__ csum,
    int K, int N, int act, int bx, int by,
    _Float16 (*As)[40], _Float16 (*Bs)[40], float* cs){
  int t = threadIdx.x, w = t>>6, lane = t&63;
  int m0 = bx*64, n0 = by*64;
  int quad = lane>>4, l15 = lane&15;
  int srow = t>>2, soff = (t&3)*8;
  f32x4 acc0 = {0.f,0.f,0.f,0.f}, acc1 = acc0, acc2 = acc0, acc3 = acc0;
  for (int k0 = 0; k0 < K; k0 += 32){
    *(uint4*)&As[srow][soff] = *(const uint4*)(A  + (size_t)(m0+srow)*K + k0 + soff);
    *(uint4*)&Bs[srow][soff] = *(const uint4*)(Bt + (size_t)(n0+srow)*K + k0 + soff);
    __syncthreads();
    f16x8 af = *(const f16x8*)&As[w*16 + l15][quad*8];
    f16x8 b0 = *(const f16x8*)&Bs[ 0 + l15][quad*8];
    f16x8 b1 = *(const f16x8*)&Bs[16 + l15][quad*8];
    f16x8 b2 = *(const f16x8*)&Bs[32 + l15][quad*8];
    f16x8 b3 = *(const f16x8*)&Bs[48 + l15][quad*8];
    acc0 = __builtin_amdgcn_mfma_f32_16x16x32_f16(af, b0, acc0, 0,0,0);
    acc1 = __builtin_amdgcn_mfma_f32_16x16x32_f16(af, b1, acc1, 0,0,0);
    acc2 = __builtin_amdgcn_mfma_f32_16x16x32_f16(af, b2, acc2, 0,0,0);
    acc3 = __builtin_amdgcn_mfma_f32_16x16x32_f16(af, b3, acc3, 0,0,0);
    __syncthreads();
  }
  f32x4 accs[4] = {acc0, acc1, acc2, acc3};
  if (csum){
    if (t < 64) cs[t] = 0.f;
    __syncthreads();
    #pragma unroll
    for (int nt=0; nt<4; ++nt){
      float pp = accs[nt][0]+accs[nt][1]+accs[nt][2]+accs[nt][3];
      atomicAdd(&cs[nt*16 + l15], pp);
    }
    __syncthreads();
    if (t < 64) atomicAdd(&csum[n0 + t], cs[t]);
  }
  #pragma unroll
  for (int nt=0; nt<4; ++nt){
    int col = n0 + nt*16 + l15;
    float bv = bias ? bias[col] : 0.f;
    #pragma unroll
    for (int r=0;r<4;r++){
      int row = m0 + w*16 + quad*4 + r;
      float v = accs[nt][r] + bv;
      if (act) v = leaky(v);
      if (Cf) Cf[(size_t)row*N + col] = v;
      if (Ch) Ch[(size_t)row*N + col] = __float2half(v);
    }
  }
}

// -------- MFMA GEMM tile, f32 inputs converted during LDS staging ------------------
template<int TRANSB>
__device__ __forceinline__ void gemm_f32(const float* __restrict__ A,
    const float* __restrict__ B, const float* __restrict__ bias,
    float* __restrict__ Cf, __half* __restrict__ Ch,
    int K, int N, int bx, int by,
    _Float16 (*As)[40], _Float16 (*Bs)[40]){
  int t = threadIdx.x, w = t>>6, lane = t&63;
  int m0 = bx*64, n0 = by*64;
  int quad = lane>>4, l15 = lane&15;
  int srow = t>>2, soff = (t&3)*8;
  f32x4 acc0 = {0.f,0.f,0.f,0.f}, acc1 = acc0, acc2 = acc0, acc3 = acc0;
  for (int k0 = 0; k0 < K; k0 += 32){
    float4 a0 = *(const float4*)(A + (size_t)(m0+srow)*K + k0 + soff);
    float4 a1 = *(const float4*)(A + (size_t)(m0+srow)*K + k0 + soff + 4);
    _Float16* ad = &As[srow][soff];
    ad[0]=(_Float16)a0.x; ad[1]=(_Float16)a0.y; ad[2]=(_Float16)a0.z; ad[3]=(_Float16)a0.w;
    ad[4]=(_Float16)a1.x; ad[5]=(_Float16)a1.y; ad[6]=(_Float16)a1.z; ad[7]=(_Float16)a1.w;
    _Float16* bd = &Bs[srow][soff];
    if (TRANSB){
      #pragma unroll
      for (int u=0;u<8;u++)
        bd[u] = (_Float16)B[(size_t)(k0+soff+u)*N + n0+srow];
    } else {
      float4 b0 = *(const float4*)(B + (size_t)(n0+srow)*K + k0 + soff);
      float4 b1 = *(const float4*)(B + (size_t)(n0+srow)*K + k0 + soff + 4);
      bd[0]=(_Float16)b0.x; bd[1]=(_Float16)b0.y; bd[2]=(_Float16)b0.z; bd[3]=(_Float16)b0.w;
      bd[4]=(_Float16)b1.x; bd[5]=(_Float16)b1.y; bd[6]=(_Float16)b1.z; bd[7]=(_Float16)b1.w;
    }
    __syncthreads();
    f16x8 af = *(const f16x8*)&As[w*16 + l15][quad*8];
    f16x8 b0 = *(const f16x8*)&Bs[ 0 + l15][quad*8];
    f16x8 b1 = *(const f16x8*)&Bs[16 + l15][quad*8];
    f16x8 b2 = *(const f16x8*)&Bs[32 + l15][quad*8];
    f16x8 b3 = *(const f16x8*)&Bs[48 + l15][quad*8];
    acc0 = __builtin_amdgcn_mfma_f32_16x16x32_f16(af, b0, acc0, 0,0,0);
    acc1 = __builtin_amdgcn_mfma_f32_16x16x32_f16(af, b1, acc1, 0,0,0);
    acc2 = __builtin_amdgcn_mfma_f32_16x16x32_f16(af, b2, acc2, 0,0,0);
    acc3 = __builtin_amdgcn_mfma_f32_16x16x32_f16(af, b3, acc3, 0,0,0);
    __syncthreads();
  }
  f32x4 accs[4] = {acc0, acc1, acc2, acc3};
  #pragma unroll
  for (int nt=0; nt<4; ++nt){
    int col = n0 + nt*16 + l15;
    float bv = bias ? bias[col] : 0.f;
    #pragma unroll
    for (int r=0;r<4;r++){
      int row = m0 + w*16 + quad*4 + r;
      float v = accs[nt][r] + bv;
      if (Cf) Cf[(size_t)row*N + col] = v;
      if (Ch) Ch[(size_t)row*N + col] = __float2half(v);
    }
  }
}

// -------- GCN aggregation F=128, WAVE-PER-NODE, ILP-8 over padded buckets ---------
template<int INS, int OUTS, int ACT>
__device__ __forceinline__ void agg128w(const __half* __restrict__ in,
    const int* __restrict__ deg, const int* __restrict__ src,
    __half* __restrict__ outp, const float* __restrict__ bias, int i){
  int lane = threadIdx.x & 63;
  int dcc = deg[i];
  float dc = rsqrtf((float)(dcc+1));
  int e0 = i*MAXDEG, e1 = e0 + dcc;
  float2 acc = make_float2(0.f, 0.f);
  for (int eb = e0; eb < e1; eb += 8){
    int m = e1 - eb; if (m > 8) m = 8;
    int r[8];
    #pragma unroll
    for (int u=0;u<8;u++) r[u] = src[(u<m) ? eb+u : eb];
    __half2 hv[8]; float sc[8];
    #pragma unroll
    for (int u=0;u<8;u++){
      hv[u] = *(const __half2*)(in + (size_t)r[u]*128 + lane*2);
      sc[u] = INS ? 1.f : rsqrtf((float)(deg[r[u]]+1));
    }
    #pragma unroll
    for (int u=0;u<8;u++){
      if (u < m){
        float2 h = __half22float2(hv[u]);
        if (INS){ acc.x += h.x; acc.y += h.y; }
        else { acc.x = fmaf(sc[u], h.x, acc.x); acc.y = fmaf(sc[u], h.y, acc.y); }
      }
    }
  }
  float2 self = __half22float2(*(const __half2*)(in + (size_t)i*128 + lane*2));
  float ss = INS ? 1.f : dc;
  float ox = dc*(ss*self.x + acc.x);
  float oy = dc*(ss*self.y + acc.y);
  if (ACT){
    ox = leaky(ox + bias[lane*2]);
    oy = leaky(oy + bias[lane*2+1]);
  }
  if (OUTS){ ox *= dc; oy *= dc; }
  *(__half2*)(outp + (size_t)i*128 + lane*2) = __floats2half2_rn(ox, oy);
}

// ------- fused attention, wave-per-node, 8-edge ILP, fold-packed wave reduction ------
__device__ __forceinline__ void attn_unit(const GP& p, int u){
  const int n = NNODES;
  int w = threadIdx.x>>6, lane = threadIdx.x&63;
  int i = u*4 + w;
  int fo = lane*4;
  uint2 qtu = *(const uint2*)(p.qth + (size_t)i*256 + fo);
  h2v q0 = as_h2(qtu.x), q1 = as_h2(qtu.y);
  float4 wbv = *(const float4*)(p.wb + fo);
  uint2 hiu  = *(const uint2*)(p.h2h + (size_t)i*256 + fo);
  float2 hia = __half22float2(*(__half2*)&hiu.x);
  float2 hib = __half22float2(*(__half2*)&hiu.y);
  float pv = hia.x*wbv.x + hia.y*wbv.y + hib.x*wbv.z + hib.y*wbv.w;
  #pragma unroll
  for (int mm=32; mm; mm>>=1) pv += __shfl_xor(pv, mm, 64);
  float base = pv + p.s0p[0];          // we = exp(d + pv + s0) == Ei*exp(d)
  int dri = p.degr[i];
  int e0 = i*MAXDEG, e1 = e0 + dri;
  float acc = 0.f, dsum = 0.f;
  int slot = lane & 7;
  for (int eb = e0; eb < e1; eb += 8){
    int m = e1 - eb; if (m > 8) m = 8;
    int j[8];
    #pragma unroll
    for (int u8=0;u8<8;u8++) j[u8] = p.csrd[(u8<m) ? eb+u8 : eb];
    uint2 hv[8]; float gv[8];
    #pragma unroll
    for (int u8=0;u8<8;u8++){
      hv[u8] = *(const uint2*)(p.h2h + (size_t)j[u8]*256 + fo);
      gv[u8] = __half2float(p.gh[(size_t)j[u8]*64 + lane]);
    }
    float d[8];
    #pragma unroll
    for (int u8=0;u8<8;u8++)
      d[u8] = __builtin_amdgcn_fdot2(q1, as_h2(hv[u8].y),
              __builtin_amdgcn_fdot2(q0, as_h2(hv[u8].x), 0.f, false), false);
    // ---- fold-packed 8-value reduction ----
    #pragma unroll
    for (int v=0;v<8;v++) d[v] += __shfl_xor(d[v], 1, 64);     // dup across bit0
    float e0_ = (lane&1) ? d[1] : d[0];
    float e1_ = (lane&1) ? d[3] : d[2];
    float e2_ = (lane&1) ? d[5] : d[4];
    float e3_ = (lane&1) ? d[7] : d[6];
    e0_ += __shfl_xor(e0_, 2, 64);  e1_ += __shfl_xor(e1_, 2, 64);  // dup bit1
    e2_ += __shfl_xor(e2_, 2, 64);  e3_ += __shfl_xor(e3_, 2, 64);
    float f0_ = (lane&2) ? e1_ : e0_;
    float f1_ = (lane&2) ? e3_ : e2_;
    f0_ += __shfl_xor(f0_, 4, 64);  f1_ += __shfl_xor(f1_, 4, 64);  // dup bit2
    float g_ = (lane&4) ? f1_ : f0_;          // lane l carries neighbor l&7
    g_ += __shfl_xor(g_,  8, 64);
    g_ += __shfl_xor(g_, 16, 64);
    g_ += __shfl_xor(g_, 32, 64);             // full 64-lane dot, dup across bits 3..5
    float wep = __expf(g_ + base);            // one exp covers 8 neighbors
    float wm = (slot < m) ? wep : 0.f;
    wm += __shfl_xor(wm, 1, 64);
    wm += __shfl_xor(wm, 2, 64);
    wm += __shfl_xor(wm, 4, 64);              // uniform across wave
    dsum += wm;
    #pragma unroll
    for (int u8=0;u8<8;u8++){
      if (u8 < m){
        float wu = __shfl(wep, u8, 64);
        acc = fmaf(wu - 1.f, gv[u8], acc);
      }
    }
  }
  float inv = 1.0f / ((float)(n - dri) + dsum);
  float di = rsqrtf((float)(p.degc[i]+1));
  p.hw3h[(size_t)i*64 + lane] = __float2half(di * (p.sw3[lane] + acc) * inv);
}

// ------- conv3 agg (pre-scaled input) + bias + leaky + residual + LN + pool ---------
__device__ __forceinline__ void zp_wave(const GP& p, int c){
  int lane = threadIdx.x & 63;
  int dcc = p.degc[c];
  float dc = rsqrtf((float)(dcc+1));
  float acc = 0.f;
  int e0 = c*MAXDEG, e1 = e0 + dcc;
  for (int eb = e0; eb < e1; eb += 8){
    int m = e1 - eb; if (m > 8) m = 8;
    int r[8];
    #pragma unroll
    for (int u=0;u<8;u++) r[u] = p.csrc[(u<m) ? eb+u : eb];
    __half hval[8];
    #pragma unroll
    for (int u=0;u<8;u++) hval[u] = p.hw3h[(size_t)r[u]*64 + lane];
    #pragma unroll
    for (int u=0;u<8;u++)
      if (u < m) acc += __half2float(hval[u]);
  }
  float self = __half2float(p.hw3h[(size_t)c*64 + lane]);   // pre-scaled by d_c
  float v = leaky(dc*(self + acc) + p.b3[lane]) + p.resid[(size_t)c*64 + lane];
  float s = v;
  #pragma unroll
  for (int mm=32; mm; mm>>=1) s += __shfl_xor(s, mm, 64);
  float mu = s * (1.0f/64.0f);
  float d = v - mu;
  float s2 = d*d;
  #pragma unroll
  for (int mm=32; mm; mm>>=1) s2 += __shfl_xor(s2, mm, 64);
  float zv = d * rsqrtf(s2*(1.0f/64.0f) + 1e-5f) * p.lng[lane] + p.lnb[lane];
  atomicMax(&p.poolpart[(c & 63)*64 + lane], fmap(zv));
}

// ---------------- final: reduce poolpart buckets + 64x16 matvec ----------------
__device__ __forceinline__ void final_unit(const GP& p, char* smem){
  int t = threadIdx.x, f = t & 63, g = t >> 6;
  unsigned (*sm)[64] = (unsigned(*)[64])smem;
  float* pool = (float*)(smem + 1024);
  unsigned mu = 0u;
  for (int b = g; b < 64; b += 4) mu = max(mu, p.poolpart[b*64 + f]);
  sm[g][f] = mu;
  __syncthreads();
  if (g == 0)
    pool[f] = funmap(max(max(sm[0][f],sm[1][f]), max(sm[2][f],sm[3][f])));
  __syncthreads();
  if (t < 16){
    float a = p.bfv[t];
    #pragma unroll
    for (int ff=0; ff<64; ++ff) a = fmaf(pool[ff], p.Wf[ff*16 + t], a);
    p.out[t] = a;
  }
}

// ======================= kernels =====================
// k_z: zero deg arrays + ALL input-only prep (fills the former 16-block idle ramp)
// [0,16): zero degc/degr int4 | [16,144): W2t | [144,208): W3t
// [208,224): zero poolpart | 224: zero sw3 | [225,481): smallvec
__global__ __launch_bounds__(256) void k_z(GP p){
  __shared__ float smv[768];
  int b = blockIdx.x, t = threadIdx.x;
  if (b < 16){
    int idx = b*256 + t;
    int4 z = {0,0,0,0};
    ((int4*)p.degc)[idx] = z;
  } else if (b < 144){             // W2[128][256] -> W2t[256][128]
    int idx = (b-16)*256 + t;
    int nn = idx >> 7, k = idx & 127;
    p.W2t[idx] = __float2half(p.W2[k*256 + nn]);
  } else if (b < 208){             // W3[256][64] -> W3t[64][256]
    int idx = (b-144)*256 + t;
    int nn = idx >> 8, k = idx & 255;
    p.W3t[idx] = __float2half(p.W3[k*64 + nn]);
  } else if (b < 224){
    p.poolpart[(b-208)*256 + t] = 0u;
  } else if (b == 224){
    if (t < 64) p.sw3[t] = 0.f;
  } else {                         // smallvec: coalesced row read + block reduce
    int c = b - 225;
    float* ra = smv; float* rb = smv + 256; float* rc = smv + 512;
    ra[t] = p.Wk[c*256 + t] * p.bq[t];
    rb[t] = p.Wq[c*256 + t] * p.bk[t];
    if (c == 0) rc[t] = p.bq[t]*p.bk[t];
    __syncthreads();
    for (int off=128; off; off>>=1){
      if (t < off){
        ra[t] += ra[t+off];
        rb[t] += rb[t+off];
        if (c == 0) rc[t] += rc[t+off];
      }
      __syncthreads();
    }
    if (t == 0){
      p.bqk[c] = ra[0];
      p.wb[c]  = rb[0];
      if (c == 0) p.s0p[0] = rc[0];
    }
  }
}

// k_pre: CSR scatter + xw1/Wqkt/resid GEMMs (f32-staged)
// [0,1024): scatter | [1024,1280): xw1 | [1280,1296): Wqkt | [1296,1424): resid
__global__ __launch_bounds__(256) void k_pre(GP p){
  __shared__ __align__(16) char smem[SMEM_BYTES];
  _Float16 (*As)[40] = (_Float16(*)[40])smem;
  _Float16 (*Bs)[40] = (_Float16(*)[40])(smem + 5120);
  int b = blockIdx.x, t = threadIdx.x;
  if (b < 1024){
    int e = b*256 + t;
    int r = p.ei[e], c = p.ei[NEDGES+e];
    int p1 = atomicAdd(&p.degc[c],1); p.csrc[c*MAXDEG + p1] = r;
    int p2 = atomicAdd(&p.degr[r],1); p.csrd[r*MAXDEG + p2] = c;
  } else if (b < 1280){            // xw1 = x@W1 (B transposed-staged from f32)
    int bb = b - 1024;
    gemm_f32<1>(p.x, p.W1, nullptr, nullptr, p.xw1h, 128, 128, bb>>1, bb&1, As, Bs);
  } else if (b < 1296){            // Wqkt = Wk@Wq^T (both f32 direct)
    int bb = b - 1280;
    gemm_f32<0>(p.Wk, p.Wq, nullptr, nullptr, p.Wqkt, 256, 256, bb&3, bb>>2, As, Bs);
  } else {                         // resid = x@Wr + br
    gemm_f32<1>(p.x, p.Wr, p.br, p.resid, nullptr, 128, 64, b-1296, 0, As, Bs);
  }
}

// conv1 aggregate (+bias+leaky), output pre-scaled by d_c -> h1'
__global__ __launch_bounds__(256) void k_agg0(GP p){
  int i = blockIdx.x*4 + (threadIdx.x>>6);
  agg128w<0,1,1>(p.xw1h, p.degc, p.csrc, p.h1h, p.b1, i);
}
// conv2 aggregate on pre-scaled input, unscaled output
__global__ __launch_bounds__(256) void k_agg1(GP p){
  int i = blockIdx.x*4 + (threadIdx.x>>6);
  agg128w<1,0,0>(p.h1h, p.degc, p.csrc, p.h1ah, nullptr, i);
}

// conv2 transform: h2 = leaky(h1a@W2 + b2)
__global__ __launch_bounds__(256) void k_gemm2(GP p){
  __shared__ __align__(16) char smem[SMEM_BYTES];
  _Float16 (*As)[40] = (_Float16(*)[40])smem;
  _Float16 (*Bs)[40] = (_Float16(*)[40])(smem + 5120);
  int b = blockIdx.x;
  gemm_tile(p.h1ah, p.W2t, p.b2, nullptr, p.h2h, nullptr, 128, 256, 1, b>>2, b&3, As, Bs, nullptr);
}

// G = h2@W3 (+colsum) and qt = h2@Wqk + bqk
__global__ __launch_bounds__(256) void k_mix2(GP p){
  __shared__ __align__(16) char smem[SMEM_BYTES];
  _Float16 (*As)[40] = (_Float16(*)[40])smem;
  _Float16 (*Bs)[40] = (_Float16(*)[40])(smem + 5120);
  float* cs = (float*)(smem + 10240);
  int b = blockIdx.x;
  if (b < 128) gemm_tile(p.h2h, p.W3t, nullptr, nullptr, p.gh, p.sw3, 256, 64, 0, b, 0, As, Bs, cs);
  else {
    int bb = b - 128;
    gemm_tile(p.h2h, p.Wqkt, p.bqk, nullptr, p.qth, nullptr, 256, 256, 0, bb>>2, bb&3, As, Bs, cs);
  }
}

__global__ __launch_bounds__(256) void k_attn(GP p){ attn_unit(p, blockIdx.x); }

__global__ __launch_bounds__(256) void k_zp(GP p){
  int c = blockIdx.x*4 + (threadIdx.x>>6);
  zp_wave(p, c);
}

__global__ __launch_bounds__(256) void k_final(GP p){
  __shared__ __align__(16) char smem[SMEM_BYTES];
  final_unit(p, smem);
}

extern "C" void kernel_launch(void* const* d_in, const int* in_sizes, int n_in,
                              void* d_out, int out_size, void* d_ws, size_t ws_size,
                              hipStream_t stream){
  const int n = NNODES, E = NEDGES;
  char* ws = (char*)d_ws; size_t off = 0;
  auto alloc = [&](size_t bytes)->void*{
    void* pp = ws + off; off += (bytes + 255) & ~(size_t)255; return pp;
  };
  GP p;
  p.x   = (const float*)d_in[0];
  p.ei  = (const int*)d_in[1];
  p.W1  = (const float*)d_in[2];  p.b1 = (const float*)d_in[3];
  p.W2  = (const float*)d_in[4];  p.b2 = (const float*)d_in[5];
  p.W3  = (const float*)d_in[6];  p.b3 = (const float*)d_in[7];
  p.Wk  = (const float*)d_in[8];  p.bk = (const float*)d_in[9];
  p.Wq  = (const float*)d_in[10]; p.bq = (const float*)d_in[11];
  p.Wr  = (const float*)d_in[12]; p.br = (const float*)d_in[13];
  p.lng = (const float*)d_in[14]; p.lnb = (const float*)d_in[15];
  p.Wf  = (const float*)d_in[16]; p.bfv = (const float*)d_in[17];
  p.out = (float*)d_out;

  // degc+degr contiguous (zeroed together by k_z)
  p.degc = (int*)alloc((size_t)n*4);
  p.degr = (int*)alloc((size_t)n*4);
  p.xw1h = (__half*)alloc((size_t)n*128*2);
  p.h1h  = (__half*)alloc((size_t)n*128*2);
  p.h1ah = (__half*)alloc((size_t)n*128*2);
  p.h2h  = (__half*)alloc((size_t)n*256*2);
  p.qth  = (__half*)alloc((size_t)n*256*2);
  p.gh   = (__half*)alloc((size_t)n*64*2);
  p.hw3h = (__half*)alloc((size_t)n*64*2);
  p.resid= (float*)alloc((size_t)n*64*4);
  p.sw3  = (float*)alloc(64*4);
  p.Wqkt = (__half*)alloc(256*256*2);
  p.W2t  = (__half*)alloc(128*256*2);
  p.W3t  = (__half*)alloc(256*64*2);
  p.bqk  = (float*)alloc(256*4);
  p.wb   = (float*)alloc(256*4);
  p.s0p  = (float*)alloc(4);
  p.csrc = (int*)alloc((size_t)n*MAXDEG*4);
  p.csrd = (int*)alloc((size_t)n*MAXDEG*4);
  p.poolpart = (unsigned*)alloc(64*64*4);

  k_z    <<<dim3(481),  256, 0, stream>>>(p);   // zero deg + transposes + smallvec
  k_pre  <<<dim3(1424), 256, 0, stream>>>(p);   // scatter + xw1/Wqkt/resid gemms
  k_agg0 <<<dim3(n/4),  256, 0, stream>>>(p);   // conv1 agg + bias + leaky, pre-scaled out
  k_agg1 <<<dim3(n/4),  256, 0, stream>>>(p);   // conv2 agg (pre-scaled in)
  k_gemm2<<<dim3(512),  256, 0, stream>>>(p);   // h2 = leaky(h1a@W2+b2)
  k_mix2 <<<dim3(640),  256, 0, stream>>>(p);   // G=h2@W3 (+colsum), qt=h2@Wqk+bqk
  k_attn <<<dim3(n/4),  256, 0, stream>>>(p);   // fused attention (packed reduce)
  k_zp   <<<dim3(n/4),  256, 0, stream>>>(p);   // conv3 agg+resid+LN+pool (wave/node)
  k_final<<<dim3(1),    256, 0, stream>>>(p);   // bucket reduce + matvec
}